// Round 1
// baseline (715.188 us; speedup 1.0000x reference)
//
#include <hip/hip_runtime.h>

#define NQ 12
#define NL 6
#define NC 10
#define DIM 4096   // 2^NQ
#define TPB 256

__global__ __launch_bounds__(TPB) void qsim_kernel(
    const float* __restrict__ x,     // [B, NQ]
    const float* __restrict__ qp,    // [NL, NQ, 3]
    const float* __restrict__ fc_w,  // [NC, NQ]
    const float* __restrict__ fc_b,  // [NC]
    float* __restrict__ out,         // [B, NC]
    int B)
{
    __shared__ float sre[DIM];
    __shared__ float sim_[DIM];
    __shared__ float gmat[NL * NQ * 8];
    __shared__ float cx[NQ], sx[NQ];
    __shared__ float red[4 * NQ];
    __shared__ float zfin[NQ];

    const int t = threadIdx.x;
    const int b = blockIdx.x;
    if (b >= B) return;

    // ---- per-block gate-matrix precompute (uniform across blocks, cheap) ----
    if (t < NL * NQ) {
        float phi = qp[t * 3 + 0];
        float th  = qp[t * 3 + 1];
        float om  = qp[t * 3 + 2];
        float st_, ct, sa, ca, sb, cb;
        sincosf(0.5f * th, &st_, &ct);
        sincosf(0.5f * (phi + om), &sa, &ca);
        sincosf(0.5f * (phi - om), &sb, &cb);
        float* g = &gmat[t * 8];
        // U00 = ep*ct ; U01 = -conj(em)*st ; U10 = em*st ; U11 = conj(ep)*ct
        g[0] =  ca * ct;  g[1] = -sa * ct;   // U00
        g[2] = -cb * st_; g[3] = -sb * st_;  // U01
        g[4] =  cb * st_; g[5] = -sb * st_;  // U10
        g[6] =  ca * ct;  g[7] =  sa * ct;   // U11
    }
    if (t < NQ) {
        float s, c;
        sincosf(0.5f * x[b * NQ + t], &s, &c);
        cx[t] = c; sx[t] = s;
    }
    __syncthreads();

    // ---- initial product state: amp[i] = prod_q (bit ? s_q : c_q), qubit q <-> bit (NQ-1-q) ----
    #pragma unroll
    for (int j = 0; j < DIM / TPB; ++j) {
        int i = t + TPB * j;
        float amp = 1.0f;
        #pragma unroll
        for (int q = 0; q < NQ; ++q) {
            amp *= ((i >> (NQ - 1 - q)) & 1) ? sx[q] : cx[q];
        }
        sre[i] = amp;
        sim_[i] = 0.0f;
    }
    __syncthreads();

    // ---- layers ----
    for (int l = 0; l < NL; ++l) {
        // Rot on every wire
        for (int q = 0; q < NQ; ++q) {
            const float* g = &gmat[(l * NQ + q) * 8];
            float u00r = g[0], u00i = g[1], u01r = g[2], u01i = g[3];
            float u10r = g[4], u10i = g[5], u11r = g[6], u11i = g[7];
            int m = 1 << (NQ - 1 - q);
            #pragma unroll
            for (int jj = 0; jj < (DIM / 2) / TPB; ++jj) {
                int p = t + TPB * jj;
                int i0 = ((p & ~(m - 1)) << 1) | (p & (m - 1));
                int i1 = i0 | m;
                float a0r = sre[i0], a0i = sim_[i0];
                float a1r = sre[i1], a1i = sim_[i1];
                float n0r = u00r * a0r - u00i * a0i + u01r * a1r - u01i * a1i;
                float n0i = u00r * a0i + u00i * a0r + u01r * a1i + u01i * a1r;
                float n1r = u10r * a0r - u10i * a0i + u11r * a1r - u11i * a1i;
                float n1i = u10r * a0i + u10i * a0r + u11r * a1i + u11i * a1r;
                sre[i0] = n0r; sim_[i0] = n0i;
                sre[i1] = n1r; sim_[i1] = n1i;
            }
            __syncthreads();
        }
        // CNOT ring: control q -> target (q+r)%NQ, applied sequentially
        int r = (l % (NQ - 1)) + 1;
        for (int q = 0; q < NQ; ++q) {
            int tq = (q + r) % NQ;
            int bc = 1 << (NQ - 1 - q);
            int bt = 1 << (NQ - 1 - tq);
            int lo = bc < bt ? bc : bt;
            int hi = bc < bt ? bt : bc;
            #pragma unroll
            for (int jj = 0; jj < (DIM / 4) / TPB; ++jj) {
                int p = t + TPB * jj;
                int i = ((p & ~(lo - 1)) << 1) | (p & (lo - 1));
                i = ((i & ~(hi - 1)) << 1) | (i & (hi - 1));
                i |= bc;            // control = 1, target currently 0
                int j2 = i ^ bt;    // partner: target = 1
                float tr = sre[i], ti = sim_[i];
                sre[i] = sre[j2];  sim_[i] = sim_[j2];
                sre[j2] = tr;      sim_[j2] = ti;
            }
            __syncthreads();
        }
    }

    // ---- PauliZ expvals ----
    float z[NQ];
    #pragma unroll
    for (int q = 0; q < NQ; ++q) z[q] = 0.0f;
    #pragma unroll
    for (int j = 0; j < DIM / TPB; ++j) {
        int i = t + TPB * j;
        float pr = sre[i] * sre[i] + sim_[i] * sim_[i];
        #pragma unroll
        for (int q = 0; q < NQ; ++q) {
            z[q] += ((i >> (NQ - 1 - q)) & 1) ? -pr : pr;
        }
    }
    // wave-level reduce (64 lanes), then cross-wave via LDS
    #pragma unroll
    for (int q = 0; q < NQ; ++q) {
        float v = z[q];
        for (int off = 32; off > 0; off >>= 1)
            v += __shfl_down(v, off, 64);
        z[q] = v;
    }
    int lane = t & 63;
    int wv = t >> 6;
    if (lane == 0) {
        #pragma unroll
        for (int q = 0; q < NQ; ++q) red[wv * NQ + q] = z[q];
    }
    __syncthreads();
    if (t < NQ) {
        zfin[t] = red[t] + red[NQ + t] + red[2 * NQ + t] + red[3 * NQ + t];
    }
    __syncthreads();

    // ---- FC layer: logits[b,c] = fc_b[c] + sum_q z[q] * fc_w[c,q] ----
    if (t < NC) {
        float acc = fc_b[t];
        #pragma unroll
        for (int q = 0; q < NQ; ++q) acc += fc_w[t * NQ + q] * zfin[q];
        out[b * NC + t] = acc;
    }
}

extern "C" void kernel_launch(void* const* d_in, const int* in_sizes, int n_in,
                              void* d_out, int out_size, void* d_ws, size_t ws_size,
                              hipStream_t stream) {
    const float* x    = (const float*)d_in[0];
    const float* qp   = (const float*)d_in[1];
    const float* fc_w = (const float*)d_in[2];
    const float* fc_b = (const float*)d_in[3];
    float* out = (float*)d_out;
    int B = in_sizes[0] / NQ;
    qsim_kernel<<<B, TPB, 0, stream>>>(x, qp, fc_w, fc_b, out, B);
}